// Round 13
// baseline (297.391 us; speedup 1.0000x reference)
//
#include <hip/hip_runtime.h>
#include <hip/hip_bf16.h>
#include <math.h>

#define B_ 8
#define C_ 256
#define N_ 1024
#define H_ 8
#define DH 96
#define BHN (C_*3*N_)
#define SC 0.10206207261596575f     // 1/sqrt(96)
#define SCL2 0.14722193f            // SC * log2(e): QK scores in log2 domain

typedef _Float16 half8 __attribute__((ext_vector_type(8)));
typedef float f32x4 __attribute__((ext_vector_type(4)));
typedef float f32x16 __attribute__((ext_vector_type(16)));

typedef __attribute__((address_space(1))) void gvoid;
typedef __attribute__((address_space(3))) void lvoid;
__device__ inline void gl_lds16(const _Float16* g, _Float16* l) {
  __builtin_amdgcn_global_load_lds((gvoid*)g, (lvoid*)l, 16, 0, 0);
}

__device__ inline float ex2(float x) { return __builtin_amdgcn_exp2f(x); }

typedef __fp16 fp16x2 __attribute__((ext_vector_type(2)));
union H2U { fp16x2 h2; unsigned u; };
__device__ inline unsigned pkh(float a, float b) {
  H2U x; x.h2 = __builtin_amdgcn_cvt_pkrtz(a, b); return x.u;
}
union PF { half8 v; unsigned u[4]; };

// v_permlane32_swap_b32: a' = [a_lo|b_lo], b' = [a_hi|b_hi]
__device__ inline void plswap(unsigned& a, unsigned& b) {
  asm volatile("v_permlane32_swap_b32 %0, %1" : "+v"(a), "+v"(b));
}

// ---------------------------------------------------------------------------
// Weights fp32 -> fp16 [4][256][256]; block 0 additionally builds the mask
// bitmask (fused to save one dispatch).
// ---------------------------------------------------------------------------
__global__ void convw_kernel(const float* __restrict__ Wq,
                             const float* __restrict__ Wk,
                             const float* __restrict__ Wv,
                             const float* __restrict__ Wp,
                             _Float16* __restrict__ Wh,
                             const unsigned* __restrict__ mraw,
                             unsigned long long* __restrict__ mb) {
  int idx = blockIdx.x * 256 + threadIdx.x;
  int e0 = idx * 8;
  const float* src = (e0 < 65536) ? Wq
                   : (e0 < 131072) ? Wk
                   : (e0 < 196608) ? Wv : Wp;
  int off = e0 & 65535;
  float4 a = *(const float4*)&src[off];
  float4 b = *(const float4*)&src[off + 4];
  _Float16 t[8] = {(_Float16)a.x, (_Float16)a.y, (_Float16)a.z, (_Float16)a.w,
                   (_Float16)b.x, (_Float16)b.y, (_Float16)b.z, (_Float16)b.w};
  *(uint4*)&Wh[e0] = *(uint4*)t;

  if (blockIdx.x == 0) {
    __shared__ int notI, notF;
    if (threadIdx.x == 0) { notI = 0; notF = 0; }
    __syncthreads();
    int li = 0, lf = 0;
    for (int i = threadIdx.x; i < 2048; i += 256) {
      unsigned w = mraw[i];
      if (w > 1u) li = 1;
      if (w != 0u && w != 0x3F800000u) lf = 1;
    }
    if (li) atomicOr(&notI, 1);
    if (lf) atomicOr(&notF, 1);
    __syncthreads();
    const int tid = threadIdx.x;
    if (tid < 128) {
      int base = tid * 64;
      unsigned long long bits = 0;
      if (!notI) {
        for (int j = 0; j < 64; ++j)
          bits |= (unsigned long long)(mraw[base + j] & 1u) << j;
      } else if (!notF) {
        for (int j = 0; j < 64; ++j)
          bits |= (unsigned long long)(mraw[base + j] != 0u ? 1 : 0) << j;
      } else {
        const unsigned char* m8 = (const unsigned char*)mraw;
        for (int j = 0; j < 64; ++j)
          bits |= (unsigned long long)(m8[base + j] ? 1 : 0) << j;
      }
      mb[tid] = bits;
    }
  }
}

// ---------------------------------------------------------------------------
// x [b][256][3072] fp32 -> XT [b][3072][256] fp16 (n-major)
// ---------------------------------------------------------------------------
__global__ __launch_bounds__(256) void convxt_kernel(
    const float* __restrict__ x, _Float16* __restrict__ XT) {
  __shared__ _Float16 T[64][65];
  const int m0 = blockIdx.x * 64;
  const int c0 = blockIdx.y * 64;
  const int b = blockIdx.z;
  const float* xb = x + (size_t)b * BHN;
  _Float16* ob = XT + (size_t)b * BHN;
  const int t = threadIdx.x;
#pragma unroll
  for (int i = 0; i < 16; ++i) {
    int e = t + i * 256;
    int c = e >> 6, m = e & 63;
    T[m][c] = (_Float16)xb[(size_t)(c0 + c) * 3072 + m0 + m];
  }
  __syncthreads();
#pragma unroll
  for (int i = 0; i < 2; ++i) {
    int e = t + i * 256;
    int m = e >> 3, ch = e & 7;
    _Float16 tmp[8];
#pragma unroll
    for (int j = 0; j < 8; ++j) tmp[j] = T[m][ch * 8 + j];
    *(uint4*)&ob[(size_t)(m0 + m) * 256 + c0 + ch * 8] = *(uint4*)tmp;
  }
}

// ---------------------------------------------------------------------------
// fp16 MFMA GEMM: O = W(256x256) @ X[b](256x3072), X n-major [n][c].
// MODE 0: scatter into packed fragment layouts for attention:
//   w=0 Qp[bh][qt32][ks6][ql32][hi2][8]  (scaled by SCL2)
//   w=1 Kp[bh][t16][ks6][kk64][hi2][8]
//   w=2 Vp[bh][t16][kt4][dt3][lq32][hi2][8]
// MODE 1: Of c-major fp32 (final out).
// ---------------------------------------------------------------------------
template <int MODE>
__global__ __launch_bounds__(256, 4) void mgemm_kernel(
    const _Float16* __restrict__ Wh, int woff,
    const _Float16* __restrict__ Xn,
    _Float16* __restrict__ O0, _Float16* __restrict__ O1,
    _Float16* __restrict__ O2, float* __restrict__ Of, int nw) {
  const int zz = blockIdx.z;
  const int w = zz % nw;
  const int b = zz / nw;
  const _Float16* Wb = Wh + (size_t)(woff + w) * 65536;
  const _Float16* Bb = Xn + (size_t)b * BHN;
  const int o0 = blockIdx.y * 128;
  const int bn0 = blockIdx.x * 128;

  __shared__ __align__(16) _Float16 Ah[4096];  // [128][32]
  __shared__ __align__(16) _Float16 Bh[4096];  // [128][32]

  const int tid = threadIdx.x;
  const int wave = tid >> 6;
  const int lane = tid & 63;
  const int lg = lane >> 4, ll = lane & 15;
  const int wm = wave >> 1, wn = wave & 1;
  const int r0 = tid >> 2, c4 = tid & 3;

  f32x4 acc[4][4];
#pragma unroll
  for (int mi = 0; mi < 4; ++mi)
#pragma unroll
    for (int ni = 0; ni < 4; ++ni) acc[mi][ni] = (f32x4){0.f, 0.f, 0.f, 0.f};

  for (int k0 = 0; k0 < 256; k0 += 32) {
    gl_lds16(Wb + (size_t)(o0 + r0) * 256 + k0 + c4 * 8, &Ah[wave * 512]);
    gl_lds16(Wb + (size_t)(o0 + 64 + r0) * 256 + k0 + c4 * 8,
             &Ah[2048 + wave * 512]);
    gl_lds16(Bb + (size_t)(bn0 + r0) * 256 + k0 + c4 * 8, &Bh[wave * 512]);
    gl_lds16(Bb + (size_t)(bn0 + 64 + r0) * 256 + k0 + c4 * 8,
             &Bh[2048 + wave * 512]);
    __syncthreads();
    half8 af[4], bf[4];
#pragma unroll
    for (int mi = 0; mi < 4; ++mi)
      af[mi] = *(const half8*)&Ah[(wm * 64 + mi * 16 + ll) * 32 + lg * 8];
#pragma unroll
    for (int ni = 0; ni < 4; ++ni)
      bf[ni] = *(const half8*)&Bh[(wn * 64 + ni * 16 + ll) * 32 + lg * 8];
#pragma unroll
    for (int mi = 0; mi < 4; ++mi)
#pragma unroll
      for (int ni = 0; ni < 4; ++ni)
        acc[mi][ni] = __builtin_amdgcn_mfma_f32_16x16x32_f16(
            af[mi], bf[ni], acc[mi][ni], 0, 0, 0);
    __syncthreads();
  }

#pragma unroll
  for (int mi = 0; mi < 4; ++mi) {
#pragma unroll
    for (int ni = 0; ni < 4; ++ni) {
      int o = o0 + wm * 64 + mi * 16 + lg * 4;   // channel (4 consecutive via r)
      int mcol = bn0 + wn * 64 + ni * 16 + ll;   // dd*1024 + token
      if constexpr (MODE == 1) {
        float* Ofb = Of + (size_t)b * BHN;
#pragma unroll
        for (int r = 0; r < 4; ++r)
          Ofb[(size_t)(o + r) * 3072 + mcol] = acc[mi][ni][r];
      } else {
        const int h = o >> 5, i = o & 31;
        const int dd = mcol >> 10, tok = mcol & 1023;
        const size_t bh8 = (size_t)(b * 8 + h);
        if (w == 2) {
          // Vp[bh][t][kt][dt=dd][lq=i(+r)][hi2][e]
          int tt = tok >> 6, kk = tok & 63;
          int kt = kk >> 4, hi2 = (kk >> 3) & 1, e = kk & 7;
          size_t base = ((((bh8 * 16 + tt) * 4 + kt) * 3 + dd) * 512) +
                        (size_t)i * 16 + hi2 * 8 + e;
#pragma unroll
          for (int r = 0; r < 4; ++r)
            O2[base + r * 16] = (_Float16)acc[mi][ni][r];
        } else {
          int dperm = dd * 32 + i;
          int pp = dperm >> 3, j0 = i & 7;
          int ks = pp >> 1, hif = pp & 1;
          float qs = (w == 0) ? SCL2 : 1.0f;
          _Float16 t4[4];
#pragma unroll
          for (int r = 0; r < 4; ++r) t4[r] = (_Float16)(acc[mi][ni][r] * qs);
          size_t idx;
          if (w == 0) {
            // Qp[bh][qt32][ks][ql][hi][j]
            idx = ((bh8 * 32 + (tok >> 5)) * 6 + ks) * 512 +
                  (size_t)(tok & 31) * 16 + hif * 8 + j0;
            *(uint2*)&O0[idx] = *(uint2*)t4;
          } else {
            // Kp[bh][t][ks][kk][hi][j]
            idx = ((bh8 * 16 + (tok >> 6)) * 6 + ks) * 1024 +
                  (size_t)(tok & 63) * 16 + hif * 8 + j0;
            *(uint2*)&O1[idx] = *(uint2*)t4;
          }
        }
      }
    }
  }
}

// ---------------------------------------------------------------------------
// Flash attention, 32x32 swapped-QK^T — LDS-free main loop, packed
// fragment-major q/k/v. KEY-SPLIT round: 8 waves/block (512 thr); waves 0-3
// handle key tiles 0-7, waves 4-7 tiles 8-15, same 128 q-rows. Pairs (w,w+4)
// combine online-softmax partials through LDS at the end. Doubles resident
// waves/SIMD (2 -> 4) to fill MFMA dependency-latency bubbles.
// Softmax in exp2 domain, defer-max THR=12, permlane P-repack.
// C/D map (HW-verified): col=lane&31, row=(r&3)+8*(r>>2)+4*(lane>>5).
// ---------------------------------------------------------------------------
__global__ __launch_bounds__(512, 4) void attn_kernel(
    const _Float16* __restrict__ Qp, const _Float16* __restrict__ Kp,
    const _Float16* __restrict__ Vp,
    const unsigned long long* __restrict__ mbits,
    _Float16* __restrict__ yT) {
  const int gid = blockIdx.x;
  const int bh = gid & 63;   // XCD = gid%8 = h: per-XCD K/V set L2-resident
  const int qt = gid >> 6;
  const int b = bh >> 3, h = bh & 7;
  const int n0 = qt * 128;

  __shared__ float CB[4 * 64 * 56];  // combine buffer: [pair][lane][56] 56KB

  const int tid = threadIdx.x;
  const int lane = tid & 63;
  const int wave = tid >> 6;         // 0..7
  const int qsub = wave & 3;
  const int half = wave >> 2;
  const int hi = lane >> 5;
  const int lq = lane & 31;
  const int wq0 = qsub * 32;
  const int t0 = half * 8;

  const size_t bh8 = (size_t)(b * 8 + h);
  const int lo16 = lq * 16 + hi * 8;   // per-lane offset within a 2KB frag blk

  // ---- Q fragments (contiguous 1KB per frag) ----
  const _Float16* Qb = Qp + (bh8 * 32 + (qt * 4 + qsub)) * 6 * 512 + lo16;
  half8 qf[6];
#pragma unroll
  for (int ks = 0; ks < 6; ++ks) qf[ks] = *(const half8*)(Qb + ks * 512);

  const _Float16* Kh = Kp + bh8 * 98304 + lo16;
  const _Float16* Vh = Vp + bh8 * 98304 + lo16;

  half8 kf[6][2];
  auto loadK = [&](int t) {
    const _Float16* Kt = Kh + t * 6144;
#pragma unroll
    for (int ks = 0; ks < 6; ++ks) {
      kf[ks][0] = *(const half8*)(Kt + ks * 1024);
      kf[ks][1] = *(const half8*)(Kt + ks * 1024 + 512);
    }
  };
  loadK(t0);

  float M = 0.f, Lh = 0.f;
  f32x16 yacc[3];
#pragma unroll
  for (int dt = 0; dt < 3; ++dt)
#pragma unroll
    for (int r = 0; r < 16; ++r) yacc[dt][r] = 0.f;

  for (int t = t0; t < t0 + 8; ++t) {
    // ---- V fragments for this tile (12 x 2KB-dense loads), issued early ----
    const _Float16* Vt = Vh + t * 6144;
    half8 vf[4][3];
#pragma unroll
    for (int kt = 0; kt < 4; ++kt)
#pragma unroll
      for (int dt = 0; dt < 3; ++dt)
        vf[kt][dt] = *(const half8*)(Vt + (kt * 3 + dt) * 512);

    const unsigned long long m64 = mbits[b * 16 + t];

    // ---- S = K.Q^T (swapped): rows=keys, cols=q ----
    f32x16 s[2];
#pragma unroll
    for (int r = 0; r < 16; ++r) { s[0][r] = 0.f; s[1][r] = 0.f; }
    __builtin_amdgcn_s_setprio(1);
#pragma unroll
    for (int ks = 0; ks < 6; ++ks) {
      s[0] = __builtin_amdgcn_mfma_f32_32x32x16_f16(kf[ks][0], qf[ks], s[0],
                                                    0, 0, 0);
      s[1] = __builtin_amdgcn_mfma_f32_32x32x16_f16(kf[ks][1], qf[ks], s[1],
                                                    0, 0, 0);
    }
    __builtin_amdgcn_s_setprio(0);

    // ---- K reload for next tile (WAR on kf; covered by softmax+PV) ----
    if (t + 1 < t0 + 8) loadK(t + 1);

    // ---- mask + local max ----
    float mx = -1e30f;
#pragma unroll
    for (int nt = 0; nt < 2; ++nt) {
      unsigned wm = (unsigned)(m64 >> (nt * 32 + 4 * hi));
#pragma unroll
      for (int r = 0; r < 16; ++r) {
        float sv = s[nt][r];
        sv = ((wm >> ((r & 3) + 8 * (r >> 2))) & 1u) ? -1e30f : sv;
        s[nt][r] = sv;
        mx = fmaxf(mx, sv);
      }
    }
    // ---- deferred max (THR=12 in log2 domain: P <= 2^12) ----
    if (__any(mx > M + 12.f)) {
      float mx2 = fmaxf(mx, __shfl_xor(mx, 32));
      float newM = fmaxf(M, mx2);
      float corr = ex2(M - newM);
      M = newM;
      Lh *= corr;
#pragma unroll
      for (int dt = 0; dt < 3; ++dt)
#pragma unroll
        for (int r = 0; r < 16; ++r) yacc[dt][r] *= corr;
    }
    float psum = 0.f;
#pragma unroll
    for (int nt = 0; nt < 2; ++nt)
#pragma unroll
      for (int r = 0; r < 16; ++r) {
        float p = ex2(s[nt][r] - M);
        s[nt][r] = p;
        psum += p;
      }
    Lh += psum;

    // ---- pack P -> fp16 B-frags via permlane32_swap ----
    unsigned pw[4][4];
#pragma unroll
    for (int nt = 0; nt < 2; ++nt)
#pragma unroll
      for (int hf = 0; hf < 2; ++hf) {
        const int bs = hf * 8;
        unsigned A0 = pkh(s[nt][bs + 0], s[nt][bs + 1]);
        unsigned A1 = pkh(s[nt][bs + 2], s[nt][bs + 3]);
        unsigned B0 = pkh(s[nt][bs + 4], s[nt][bs + 5]);
        unsigned B1 = pkh(s[nt][bs + 6], s[nt][bs + 7]);
        plswap(A0, B0);
        plswap(A1, B1);
        pw[nt * 2 + hf][0] = A0;
        pw[nt * 2 + hf][1] = A1;
        pw[nt * 2 + hf][2] = B0;
        pw[nt * 2 + hf][3] = B1;
      }

    // ---- PV: one unbroken 12-MFMA cluster ----
    __builtin_amdgcn_s_setprio(1);
#pragma unroll
    for (int kt = 0; kt < 4; ++kt) {
      PF pf;
      pf.u[0] = pw[kt][0];
      pf.u[1] = pw[kt][1];
      pf.u[2] = pw[kt][2];
      pf.u[3] = pw[kt][3];
#pragma unroll
      for (int dt = 0; dt < 3; ++dt)
        yacc[dt] = __builtin_amdgcn_mfma_f32_32x32x16_f16(
            vf[kt][dt], pf.v, yacc[dt], 0, 0, 0);
    }
    __builtin_amdgcn_s_setprio(0);
  }

  // ---- key-split combine: pairs (w, w+4) share q-rows ----
  float Lown = Lh + __shfl_xor(Lh, 32);   // merge hi halves (M is hi-uniform)
  if (wave >= 4) {
    int base = ((wave - 4) * 64 + lane) * 56;
#pragma unroll
    for (int dt = 0; dt < 3; ++dt)
#pragma unroll
      for (int g = 0; g < 4; ++g)
        *(f32x4*)&CB[base + dt * 16 + g * 4] =
            (f32x4){yacc[dt][g * 4 + 0], yacc[dt][g * 4 + 1],
                    yacc[dt][g * 4 + 2], yacc[dt][g * 4 + 3]};
    CB[base + 48] = M;
    CB[base + 49] = Lown;
  }
  __syncthreads();
  if (wave < 4) {
    int base = (wave * 64 + lane) * 56;
    float Mb = CB[base + 48], Lb = CB[base + 49];
    float newM = fmaxf(M, Mb);
    float ca = ex2(M - newM), cb = ex2(Mb - newM);
    float L = Lown * ca + Lb * cb;
    float inv = (L > 0.f) ? 1.f / L : 0.f;
    _Float16* yb = yT + (size_t)b * BHN;
#pragma unroll
    for (int dt = 0; dt < 3; ++dt) {
      _Float16* rowp =
          yb + (size_t)(dt * 1024 + n0 + wq0 + lq) * 256 + h * 32 + hi * 4;
#pragma unroll
      for (int g = 0; g < 4; ++g) {
        _Float16 t4[4];
#pragma unroll
        for (int j = 0; j < 4; ++j) {
          float yo = yacc[dt][g * 4 + j] * ca +
                     CB[base + dt * 16 + g * 4 + j] * cb;
          t4[j] = (_Float16)(yo * inv);
        }
        *(uint2*)(rowp + g * 8) = *(uint2*)t4;
      }
    }
  }
}

// ---------------------------------------------------------------------------
extern "C" void kernel_launch(void* const* d_in, const int* in_sizes, int n_in,
                              void* d_out, int out_size, void* d_ws,
                              size_t ws_size, hipStream_t stream) {
  const float* x = (const float*)d_in[0];
  const float* Wq = (const float*)d_in[1];
  const float* Wk = (const float*)d_in[2];
  const float* Wv = (const float*)d_in[3];
  const float* Wp = (const float*)d_in[4];
  const unsigned* mask = (const unsigned*)d_in[5];
  float* out = (float*)d_out;

  _Float16* Wh = (_Float16*)d_ws;                   // 0.5 MB
  _Float16* XT = Wh + 4 * 65536;                    // 12.6 MB n-major
  _Float16* Qp = XT + (size_t)B_ * BHN;             // 12.6 MB packed frags
  _Float16* Kp = Qp + (size_t)B_ * BHN;             // 12.6 MB packed frags
  _Float16* Vp = Kp + (size_t)B_ * BHN;             // 12.6 MB packed frags
  _Float16* yT = Vp + (size_t)B_ * BHN;             // 12.6 MB n-major
  unsigned long long* mb = (unsigned long long*)(yT + (size_t)B_ * BHN);

  convw_kernel<<<128, 256, 0, stream>>>(Wq, Wk, Wv, Wp, Wh, mask, mb);
  convxt_kernel<<<dim3(48, 4, B_), 256, 0, stream>>>(x, XT);

  dim3 g1(24, 2, B_ * 3);
  mgemm_kernel<0><<<g1, 256, 0, stream>>>(Wh, 0, XT, Qp, Kp, Vp, nullptr, 3);

  attn_kernel<<<dim3(512), 512, 0, stream>>>(Qp, Kp, Vp, mb, yT);

  dim3 g3(24, 2, B_);
  mgemm_kernel<1><<<g3, 256, 0, stream>>>(Wh, 3, yT, nullptr, nullptr, nullptr,
                                          out, 1);
}

// Round 14
// 94.642 us; speedup vs baseline: 3.1423x; 3.1423x over previous
//
#include <hip/hip_runtime.h>
#include <hip/hip_bf16.h>
#include <math.h>

#define B_ 8
#define C_ 256
#define N_ 1024
#define H_ 8
#define DH 96
#define BHN (C_*3*N_)
#define SC 0.10206207261596575f     // 1/sqrt(96)
#define SCL2 0.14722193f            // SC * log2(e): QK scores in log2 domain

typedef _Float16 half8 __attribute__((ext_vector_type(8)));
typedef float f32x4 __attribute__((ext_vector_type(4)));
typedef float f32x16 __attribute__((ext_vector_type(16)));

typedef __attribute__((address_space(1))) void gvoid;
typedef __attribute__((address_space(3))) void lvoid;
__device__ inline void gl_lds16(const _Float16* g, _Float16* l) {
  __builtin_amdgcn_global_load_lds((gvoid*)g, (lvoid*)l, 16, 0, 0);
}

__device__ inline float ex2(float x) { return __builtin_amdgcn_exp2f(x); }

typedef __fp16 fp16x2 __attribute__((ext_vector_type(2)));
union H2U { fp16x2 h2; unsigned u; };
__device__ inline unsigned pkh(float a, float b) {
  H2U x; x.h2 = __builtin_amdgcn_cvt_pkrtz(a, b); return x.u;
}
union PF { half8 v; unsigned u[4]; };

// v_permlane32_swap_b32: a' = [a_lo|b_lo], b' = [a_hi|b_hi]
__device__ inline void plswap(unsigned& a, unsigned& b) {
  asm volatile("v_permlane32_swap_b32 %0, %1" : "+v"(a), "+v"(b));
}

// ---------------------------------------------------------------------------
// Weights fp32 -> fp16 [4][256][256]; block 0 additionally builds the mask
// bitmask (fused to save one dispatch).
// ---------------------------------------------------------------------------
__global__ void convw_kernel(const float* __restrict__ Wq,
                             const float* __restrict__ Wk,
                             const float* __restrict__ Wv,
                             const float* __restrict__ Wp,
                             _Float16* __restrict__ Wh,
                             const unsigned* __restrict__ mraw,
                             unsigned long long* __restrict__ mb) {
  int idx = blockIdx.x * 256 + threadIdx.x;
  int e0 = idx * 8;
  const float* src = (e0 < 65536) ? Wq
                   : (e0 < 131072) ? Wk
                   : (e0 < 196608) ? Wv : Wp;
  int off = e0 & 65535;
  float4 a = *(const float4*)&src[off];
  float4 b = *(const float4*)&src[off + 4];
  _Float16 t[8] = {(_Float16)a.x, (_Float16)a.y, (_Float16)a.z, (_Float16)a.w,
                   (_Float16)b.x, (_Float16)b.y, (_Float16)b.z, (_Float16)b.w};
  *(uint4*)&Wh[e0] = *(uint4*)t;

  if (blockIdx.x == 0) {
    __shared__ int notI, notF;
    if (threadIdx.x == 0) { notI = 0; notF = 0; }
    __syncthreads();
    int li = 0, lf = 0;
    for (int i = threadIdx.x; i < 2048; i += 256) {
      unsigned w = mraw[i];
      if (w > 1u) li = 1;
      if (w != 0u && w != 0x3F800000u) lf = 1;
    }
    if (li) atomicOr(&notI, 1);
    if (lf) atomicOr(&notF, 1);
    __syncthreads();
    const int tid = threadIdx.x;
    if (tid < 128) {
      int base = tid * 64;
      unsigned long long bits = 0;
      if (!notI) {
        for (int j = 0; j < 64; ++j)
          bits |= (unsigned long long)(mraw[base + j] & 1u) << j;
      } else if (!notF) {
        for (int j = 0; j < 64; ++j)
          bits |= (unsigned long long)(mraw[base + j] != 0u ? 1 : 0) << j;
      } else {
        const unsigned char* m8 = (const unsigned char*)mraw;
        for (int j = 0; j < 64; ++j)
          bits |= (unsigned long long)(m8[base + j] ? 1 : 0) << j;
      }
      mb[tid] = bits;
    }
  }
}

// ---------------------------------------------------------------------------
// x [b][256][3072] fp32 -> XT [b][3072][256] fp16 (n-major)
// ---------------------------------------------------------------------------
__global__ __launch_bounds__(256) void convxt_kernel(
    const float* __restrict__ x, _Float16* __restrict__ XT) {
  __shared__ _Float16 T[64][65];
  const int m0 = blockIdx.x * 64;
  const int c0 = blockIdx.y * 64;
  const int b = blockIdx.z;
  const float* xb = x + (size_t)b * BHN;
  _Float16* ob = XT + (size_t)b * BHN;
  const int t = threadIdx.x;
#pragma unroll
  for (int i = 0; i < 16; ++i) {
    int e = t + i * 256;
    int c = e >> 6, m = e & 63;
    T[m][c] = (_Float16)xb[(size_t)(c0 + c) * 3072 + m0 + m];
  }
  __syncthreads();
#pragma unroll
  for (int i = 0; i < 2; ++i) {
    int e = t + i * 256;
    int m = e >> 3, ch = e & 7;
    _Float16 tmp[8];
#pragma unroll
    for (int j = 0; j < 8; ++j) tmp[j] = T[m][ch * 8 + j];
    *(uint4*)&ob[(size_t)(m0 + m) * 256 + c0 + ch * 8] = *(uint4*)tmp;
  }
}

// ---------------------------------------------------------------------------
// fp16 MFMA GEMM: O = W(256x256) @ X[b](256x3072), X n-major [n][c].
// MODE 0: scatter into packed fragment layouts for attention:
//   w=0 Qp[bh][qt32][ks6][ql32][hi2][8]  (scaled by SCL2)
//   w=1 Kp[bh][t16][ks6][kk64][hi2][8]
//   w=2 Vp[bh][t16][kt4][dt3][lq32][hi2][8]
// MODE 1: Of c-major fp32 (final out).
// ---------------------------------------------------------------------------
template <int MODE>
__global__ __launch_bounds__(256, 4) void mgemm_kernel(
    const _Float16* __restrict__ Wh, int woff,
    const _Float16* __restrict__ Xn,
    _Float16* __restrict__ O0, _Float16* __restrict__ O1,
    _Float16* __restrict__ O2, float* __restrict__ Of, int nw) {
  const int zz = blockIdx.z;
  const int w = zz % nw;
  const int b = zz / nw;
  const _Float16* Wb = Wh + (size_t)(woff + w) * 65536;
  const _Float16* Bb = Xn + (size_t)b * BHN;
  const int o0 = blockIdx.y * 128;
  const int bn0 = blockIdx.x * 128;

  __shared__ __align__(16) _Float16 Ah[4096];  // [128][32]
  __shared__ __align__(16) _Float16 Bh[4096];  // [128][32]

  const int tid = threadIdx.x;
  const int wave = tid >> 6;
  const int lane = tid & 63;
  const int lg = lane >> 4, ll = lane & 15;
  const int wm = wave >> 1, wn = wave & 1;
  const int r0 = tid >> 2, c4 = tid & 3;

  f32x4 acc[4][4];
#pragma unroll
  for (int mi = 0; mi < 4; ++mi)
#pragma unroll
    for (int ni = 0; ni < 4; ++ni) acc[mi][ni] = (f32x4){0.f, 0.f, 0.f, 0.f};

  for (int k0 = 0; k0 < 256; k0 += 32) {
    gl_lds16(Wb + (size_t)(o0 + r0) * 256 + k0 + c4 * 8, &Ah[wave * 512]);
    gl_lds16(Wb + (size_t)(o0 + 64 + r0) * 256 + k0 + c4 * 8,
             &Ah[2048 + wave * 512]);
    gl_lds16(Bb + (size_t)(bn0 + r0) * 256 + k0 + c4 * 8, &Bh[wave * 512]);
    gl_lds16(Bb + (size_t)(bn0 + 64 + r0) * 256 + k0 + c4 * 8,
             &Bh[2048 + wave * 512]);
    __syncthreads();
    half8 af[4], bf[4];
#pragma unroll
    for (int mi = 0; mi < 4; ++mi)
      af[mi] = *(const half8*)&Ah[(wm * 64 + mi * 16 + ll) * 32 + lg * 8];
#pragma unroll
    for (int ni = 0; ni < 4; ++ni)
      bf[ni] = *(const half8*)&Bh[(wn * 64 + ni * 16 + ll) * 32 + lg * 8];
#pragma unroll
    for (int mi = 0; mi < 4; ++mi)
#pragma unroll
      for (int ni = 0; ni < 4; ++ni)
        acc[mi][ni] = __builtin_amdgcn_mfma_f32_16x16x32_f16(
            af[mi], bf[ni], acc[mi][ni], 0, 0, 0);
    __syncthreads();
  }

#pragma unroll
  for (int mi = 0; mi < 4; ++mi) {
#pragma unroll
    for (int ni = 0; ni < 4; ++ni) {
      int o = o0 + wm * 64 + mi * 16 + lg * 4;   // channel (4 consecutive via r)
      int mcol = bn0 + wn * 64 + ni * 16 + ll;   // dd*1024 + token
      if constexpr (MODE == 1) {
        float* Ofb = Of + (size_t)b * BHN;
#pragma unroll
        for (int r = 0; r < 4; ++r)
          Ofb[(size_t)(o + r) * 3072 + mcol] = acc[mi][ni][r];
      } else {
        const int h = o >> 5, i = o & 31;
        const int dd = mcol >> 10, tok = mcol & 1023;
        const size_t bh8 = (size_t)(b * 8 + h);
        if (w == 2) {
          // Vp[bh][t][kt][dt=dd][lq=i(+r)][hi2][e]
          int tt = tok >> 6, kk = tok & 63;
          int kt = kk >> 4, hi2 = (kk >> 3) & 1, e = kk & 7;
          size_t base = ((((bh8 * 16 + tt) * 4 + kt) * 3 + dd) * 512) +
                        (size_t)i * 16 + hi2 * 8 + e;
#pragma unroll
          for (int r = 0; r < 4; ++r)
            O2[base + r * 16] = (_Float16)acc[mi][ni][r];
        } else {
          int dperm = dd * 32 + i;
          int pp = dperm >> 3, j0 = i & 7;
          int ks = pp >> 1, hif = pp & 1;
          float qs = (w == 0) ? SCL2 : 1.0f;
          _Float16 t4[4];
#pragma unroll
          for (int r = 0; r < 4; ++r) t4[r] = (_Float16)(acc[mi][ni][r] * qs);
          size_t idx;
          if (w == 0) {
            // Qp[bh][qt32][ks][ql][hi][j]
            idx = ((bh8 * 32 + (tok >> 5)) * 6 + ks) * 512 +
                  (size_t)(tok & 31) * 16 + hif * 8 + j0;
            *(uint2*)&O0[idx] = *(uint2*)t4;
          } else {
            // Kp[bh][t][ks][kk][hi][j]
            idx = ((bh8 * 16 + (tok >> 6)) * 6 + ks) * 1024 +
                  (size_t)(tok & 63) * 16 + hif * 8 + j0;
            *(uint2*)&O1[idx] = *(uint2*)t4;
          }
        }
      }
    }
  }
}

// ---------------------------------------------------------------------------
// Flash attention, 32x32 swapped-QK^T — LDS-free main loop, packed
// fragment-major q/k/v. KEY-SPLIT: 8 waves/block (512 thr); waves 0-3 do key
// tiles 0-7, waves 4-7 do tiles 8-15, same 128 q-rows; pairs (w,w+4) combine
// via LDS at the end. __launch_bounds__(512,2): 2 BLOCKS/CU (CUDA semantics
// confirmed by r13 spill) = 16 waves/CU = 4 waves/SIMD with 128-VGPR cap,
// which the ~112-124 live state fits — doubles TLP without spilling.
// Softmax in exp2 domain, defer-max THR=12, permlane P-repack.
// C/D map (HW-verified): col=lane&31, row=(r&3)+8*(r>>2)+4*(lane>>5).
// ---------------------------------------------------------------------------
__global__ __launch_bounds__(512, 2) void attn_kernel(
    const _Float16* __restrict__ Qp, const _Float16* __restrict__ Kp,
    const _Float16* __restrict__ Vp,
    const unsigned long long* __restrict__ mbits,
    _Float16* __restrict__ yT) {
  const int gid = blockIdx.x;
  const int bh = gid & 63;   // XCD = gid%8 = h: per-XCD K/V set L2-resident
  const int qt = gid >> 6;
  const int b = bh >> 3, h = bh & 7;
  const int n0 = qt * 128;

  __shared__ float CB[4 * 64 * 56];  // combine buffer: [pair][lane][56] 56KB

  const int tid = threadIdx.x;
  const int lane = tid & 63;
  const int wave = tid >> 6;         // 0..7
  const int qsub = wave & 3;
  const int half = wave >> 2;
  const int hi = lane >> 5;
  const int lq = lane & 31;
  const int wq0 = qsub * 32;
  const int t0 = half * 8;

  const size_t bh8 = (size_t)(b * 8 + h);
  const int lo16 = lq * 16 + hi * 8;   // per-lane offset within a 2KB frag blk

  // ---- Q fragments (contiguous 1KB per frag) ----
  const _Float16* Qb = Qp + (bh8 * 32 + (qt * 4 + qsub)) * 6 * 512 + lo16;
  half8 qf[6];
#pragma unroll
  for (int ks = 0; ks < 6; ++ks) qf[ks] = *(const half8*)(Qb + ks * 512);

  const _Float16* Kh = Kp + bh8 * 98304 + lo16;
  const _Float16* Vh = Vp + bh8 * 98304 + lo16;

  half8 kf[6][2];
  auto loadK = [&](int t) {
    const _Float16* Kt = Kh + t * 6144;
#pragma unroll
    for (int ks = 0; ks < 6; ++ks) {
      kf[ks][0] = *(const half8*)(Kt + ks * 1024);
      kf[ks][1] = *(const half8*)(Kt + ks * 1024 + 512);
    }
  };
  loadK(t0);

  float M = 0.f, Lh = 0.f;
  f32x16 yacc[3];
#pragma unroll
  for (int dt = 0; dt < 3; ++dt)
#pragma unroll
    for (int r = 0; r < 16; ++r) yacc[dt][r] = 0.f;

  for (int t = t0; t < t0 + 8; ++t) {
    // ---- V fragments for this tile (12 x 2KB-dense loads), issued early ----
    const _Float16* Vt = Vh + t * 6144;
    half8 vf[4][3];
#pragma unroll
    for (int kt = 0; kt < 4; ++kt)
#pragma unroll
      for (int dt = 0; dt < 3; ++dt)
        vf[kt][dt] = *(const half8*)(Vt + (kt * 3 + dt) * 512);

    const unsigned long long m64 = mbits[b * 16 + t];

    // ---- S = K.Q^T (swapped): rows=keys, cols=q ----
    f32x16 s[2];
#pragma unroll
    for (int r = 0; r < 16; ++r) { s[0][r] = 0.f; s[1][r] = 0.f; }
    __builtin_amdgcn_s_setprio(1);
#pragma unroll
    for (int ks = 0; ks < 6; ++ks) {
      s[0] = __builtin_amdgcn_mfma_f32_32x32x16_f16(kf[ks][0], qf[ks], s[0],
                                                    0, 0, 0);
      s[1] = __builtin_amdgcn_mfma_f32_32x32x16_f16(kf[ks][1], qf[ks], s[1],
                                                    0, 0, 0);
    }
    __builtin_amdgcn_s_setprio(0);

    // ---- K reload for next tile (WAR on kf; covered by softmax+PV) ----
    if (t + 1 < t0 + 8) loadK(t + 1);

    // ---- mask + local max ----
    float mx = -1e30f;
#pragma unroll
    for (int nt = 0; nt < 2; ++nt) {
      unsigned wm = (unsigned)(m64 >> (nt * 32 + 4 * hi));
#pragma unroll
      for (int r = 0; r < 16; ++r) {
        float sv = s[nt][r];
        sv = ((wm >> ((r & 3) + 8 * (r >> 2))) & 1u) ? -1e30f : sv;
        s[nt][r] = sv;
        mx = fmaxf(mx, sv);
      }
    }
    // ---- deferred max (THR=12 in log2 domain: P <= 2^12) ----
    if (__any(mx > M + 12.f)) {
      float mx2 = fmaxf(mx, __shfl_xor(mx, 32));
      float newM = fmaxf(M, mx2);
      float corr = ex2(M - newM);
      M = newM;
      Lh *= corr;
#pragma unroll
      for (int dt = 0; dt < 3; ++dt)
#pragma unroll
        for (int r = 0; r < 16; ++r) yacc[dt][r] *= corr;
    }
    float psum = 0.f;
#pragma unroll
    for (int nt = 0; nt < 2; ++nt)
#pragma unroll
      for (int r = 0; r < 16; ++r) {
        float p = ex2(s[nt][r] - M);
        s[nt][r] = p;
        psum += p;
      }
    Lh += psum;

    // ---- pack P -> fp16 B-frags via permlane32_swap ----
    unsigned pw[4][4];
#pragma unroll
    for (int nt = 0; nt < 2; ++nt)
#pragma unroll
      for (int hf = 0; hf < 2; ++hf) {
        const int bs = hf * 8;
        unsigned A0 = pkh(s[nt][bs + 0], s[nt][bs + 1]);
        unsigned A1 = pkh(s[nt][bs + 2], s[nt][bs + 3]);
        unsigned B0 = pkh(s[nt][bs + 4], s[nt][bs + 5]);
        unsigned B1 = pkh(s[nt][bs + 6], s[nt][bs + 7]);
        plswap(A0, B0);
        plswap(A1, B1);
        pw[nt * 2 + hf][0] = A0;
        pw[nt * 2 + hf][1] = A1;
        pw[nt * 2 + hf][2] = B0;
        pw[nt * 2 + hf][3] = B1;
      }

    // ---- PV: one unbroken 12-MFMA cluster ----
    __builtin_amdgcn_s_setprio(1);
#pragma unroll
    for (int kt = 0; kt < 4; ++kt) {
      PF pf;
      pf.u[0] = pw[kt][0];
      pf.u[1] = pw[kt][1];
      pf.u[2] = pw[kt][2];
      pf.u[3] = pw[kt][3];
#pragma unroll
      for (int dt = 0; dt < 3; ++dt)
        yacc[dt] = __builtin_amdgcn_mfma_f32_32x32x16_f16(
            vf[kt][dt], pf.v, yacc[dt], 0, 0, 0);
    }
    __builtin_amdgcn_s_setprio(0);
  }

  // ---- key-split combine: pairs (w, w+4) share q-rows ----
  float Lown = Lh + __shfl_xor(Lh, 32);   // merge hi halves (M is hi-uniform)
  if (wave >= 4) {
    int base = ((wave - 4) * 64 + lane) * 56;
#pragma unroll
    for (int dt = 0; dt < 3; ++dt)
#pragma unroll
      for (int g = 0; g < 4; ++g)
        *(f32x4*)&CB[base + dt * 16 + g * 4] =
            (f32x4){yacc[dt][g * 4 + 0], yacc[dt][g * 4 + 1],
                    yacc[dt][g * 4 + 2], yacc[dt][g * 4 + 3]};
    CB[base + 48] = M;
    CB[base + 49] = Lown;
  }
  __syncthreads();
  if (wave < 4) {
    int base = (wave * 64 + lane) * 56;
    float Mb = CB[base + 48], Lb = CB[base + 49];
    float newM = fmaxf(M, Mb);
    float ca = ex2(M - newM), cb = ex2(Mb - newM);
    float L = Lown * ca + Lb * cb;
    float inv = (L > 0.f) ? 1.f / L : 0.f;
    _Float16* yb = yT + (size_t)b * BHN;
#pragma unroll
    for (int dt = 0; dt < 3; ++dt) {
      _Float16* rowp =
          yb + (size_t)(dt * 1024 + n0 + wq0 + lq) * 256 + h * 32 + hi * 4;
#pragma unroll
      for (int g = 0; g < 4; ++g) {
        _Float16 t4[4];
#pragma unroll
        for (int j = 0; j < 4; ++j) {
          float yo = yacc[dt][g * 4 + j] * ca +
                     CB[base + dt * 16 + g * 4 + j] * cb;
          t4[j] = (_Float16)(yo * inv);
        }
        *(uint2*)(rowp + g * 8) = *(uint2*)t4;
      }
    }
  }
}

// ---------------------------------------------------------------------------
extern "C" void kernel_launch(void* const* d_in, const int* in_sizes, int n_in,
                              void* d_out, int out_size, void* d_ws,
                              size_t ws_size, hipStream_t stream) {
  const float* x = (const float*)d_in[0];
  const float* Wq = (const float*)d_in[1];
  const float* Wk = (const float*)d_in[2];
  const float* Wv = (const float*)d_in[3];
  const float* Wp = (const float*)d_in[4];
  const unsigned* mask = (const unsigned*)d_in[5];
  float* out = (float*)d_out;

  _Float16* Wh = (_Float16*)d_ws;                   // 0.5 MB
  _Float16* XT = Wh + 4 * 65536;                    // 12.6 MB n-major
  _Float16* Qp = XT + (size_t)B_ * BHN;             // 12.6 MB packed frags
  _Float16* Kp = Qp + (size_t)B_ * BHN;             // 12.6 MB packed frags
  _Float16* Vp = Kp + (size_t)B_ * BHN;             // 12.6 MB packed frags
  _Float16* yT = Vp + (size_t)B_ * BHN;             // 12.6 MB n-major
  unsigned long long* mb = (unsigned long long*)(yT + (size_t)B_ * BHN);

  convw_kernel<<<128, 256, 0, stream>>>(Wq, Wk, Wv, Wp, Wh, mask, mb);
  convxt_kernel<<<dim3(48, 4, B_), 256, 0, stream>>>(x, XT);

  dim3 g1(24, 2, B_ * 3);
  mgemm_kernel<0><<<g1, 256, 0, stream>>>(Wh, 0, XT, Qp, Kp, Vp, nullptr, 3);

  attn_kernel<<<dim3(512), 512, 0, stream>>>(Qp, Kp, Vp, mb, yT);

  dim3 g3(24, 2, B_);
  mgemm_kernel<1><<<g3, 256, 0, stream>>>(Wh, 3, yT, nullptr, nullptr, nullptr,
                                          out, 1);
}

// Round 15
// 90.293 us; speedup vs baseline: 3.2936x; 1.0482x over previous
//
#include <hip/hip_runtime.h>
#include <hip/hip_bf16.h>
#include <math.h>

#define B_ 8
#define C_ 256
#define N_ 1024
#define H_ 8
#define DH 96
#define BHN (C_*3*N_)
#define SC 0.10206207261596575f     // 1/sqrt(96)
#define SCL2 0.14722193f            // SC * log2(e): QK scores in log2 domain

typedef _Float16 half8 __attribute__((ext_vector_type(8)));
typedef float f32x4 __attribute__((ext_vector_type(4)));
typedef float f32x16 __attribute__((ext_vector_type(16)));

typedef __attribute__((address_space(1))) void gvoid;
typedef __attribute__((address_space(3))) void lvoid;
__device__ inline void gl_lds16(const _Float16* g, _Float16* l) {
  __builtin_amdgcn_global_load_lds((gvoid*)g, (lvoid*)l, 16, 0, 0);
}

__device__ inline float ex2(float x) { return __builtin_amdgcn_exp2f(x); }

typedef __fp16 fp16x2 __attribute__((ext_vector_type(2)));
union H2U { fp16x2 h2; unsigned u; };
__device__ inline unsigned pkh(float a, float b) {
  H2U x; x.h2 = __builtin_amdgcn_cvt_pkrtz(a, b); return x.u;
}
union PF { half8 v; unsigned u[4]; };

// v_permlane32_swap_b32: a' = [a_lo|b_lo], b' = [a_hi|b_hi]
__device__ inline void plswap(unsigned& a, unsigned& b) {
  asm volatile("v_permlane32_swap_b32 %0, %1" : "+v"(a), "+v"(b));
}

// ---------------------------------------------------------------------------
// Fused prep kernel. z<8: transpose-convert x [b][256][3072] fp32 ->
// XT [b][3072][256] fp16. z==8: flat block id 0..127 convert W fp32->fp16
// ([4][256][256]); block 128 builds the mask bitmask.
// ---------------------------------------------------------------------------
__global__ __launch_bounds__(256) void prep_kernel(
    const float* __restrict__ x, _Float16* __restrict__ XT,
    const float* __restrict__ Wq, const float* __restrict__ Wk,
    const float* __restrict__ Wv, const float* __restrict__ Wp,
    _Float16* __restrict__ Wh, const unsigned* __restrict__ mraw,
    unsigned long long* __restrict__ mb) {
  if (blockIdx.z == 8) {
    int bid = blockIdx.y * 48 + blockIdx.x;
    if (bid < 128) {
      int idx = bid * 256 + threadIdx.x;
      int e0 = idx * 8;
      const float* src = (e0 < 65536) ? Wq
                       : (e0 < 131072) ? Wk
                       : (e0 < 196608) ? Wv : Wp;
      int off = e0 & 65535;
      float4 a = *(const float4*)&src[off];
      float4 b = *(const float4*)&src[off + 4];
      _Float16 t[8] = {(_Float16)a.x, (_Float16)a.y, (_Float16)a.z,
                       (_Float16)a.w, (_Float16)b.x, (_Float16)b.y,
                       (_Float16)b.z, (_Float16)b.w};
      *(uint4*)&Wh[e0] = *(uint4*)t;
    } else if (bid == 128) {
      __shared__ int notI, notF;
      if (threadIdx.x == 0) { notI = 0; notF = 0; }
      __syncthreads();
      int li = 0, lf = 0;
      for (int i = threadIdx.x; i < 2048; i += 256) {
        unsigned w = mraw[i];
        if (w > 1u) li = 1;
        if (w != 0u && w != 0x3F800000u) lf = 1;
      }
      if (li) atomicOr(&notI, 1);
      if (lf) atomicOr(&notF, 1);
      __syncthreads();
      const int tid = threadIdx.x;
      if (tid < 128) {
        int base = tid * 64;
        unsigned long long bits = 0;
        if (!notI) {
          for (int j = 0; j < 64; ++j)
            bits |= (unsigned long long)(mraw[base + j] & 1u) << j;
        } else if (!notF) {
          for (int j = 0; j < 64; ++j)
            bits |= (unsigned long long)(mraw[base + j] != 0u ? 1 : 0) << j;
        } else {
          const unsigned char* m8 = (const unsigned char*)mraw;
          for (int j = 0; j < 64; ++j)
            bits |= (unsigned long long)(m8[base + j] ? 1 : 0) << j;
        }
        mb[tid] = bits;
      }
    }
    return;
  }

  __shared__ _Float16 T[64][65];
  const int m0 = blockIdx.x * 64;
  const int c0 = blockIdx.y * 64;
  const int b = blockIdx.z;
  const float* xb = x + (size_t)b * BHN;
  _Float16* ob = XT + (size_t)b * BHN;
  const int t = threadIdx.x;
#pragma unroll
  for (int i = 0; i < 16; ++i) {
    int e = t + i * 256;
    int c = e >> 6, m = e & 63;
    T[m][c] = (_Float16)xb[(size_t)(c0 + c) * 3072 + m0 + m];
  }
  __syncthreads();
#pragma unroll
  for (int i = 0; i < 2; ++i) {
    int e = t + i * 256;
    int m = e >> 3, ch = e & 7;
    _Float16 tmp[8];
#pragma unroll
    for (int j = 0; j < 8; ++j) tmp[j] = T[m][ch * 8 + j];
    *(uint4*)&ob[(size_t)(m0 + m) * 256 + c0 + ch * 8] = *(uint4*)tmp;
  }
}

// ---------------------------------------------------------------------------
// fp16 MFMA GEMM: O = W(256x256) @ X[b](256x3072), X n-major [n][c].
// BK=64 (8 barriers/block instead of 16). Row stride 128B would be a 16-way
// bank conflict -> both-sides XOR chunk swizzle (rule #21): LDS dest linear,
// global SOURCE pre-swizzled (chunk^row&7), ds_read swizzled the same way.
// MODE 0: scatter into packed fragment layouts for attention:
//   w=0 Qp[bh][qt32][ks6][ql32][hi2][8]  (scaled by SCL2)
//   w=1 Kp[bh][t16][ks6][kk64][hi2][8]
//   w=2 Vp[bh][t16][kt4][dt3][lq32][hi2][8]
// MODE 1: Of c-major fp32 (final out).
// ---------------------------------------------------------------------------
template <int MODE>
__global__ __launch_bounds__(256, 4) void mgemm_kernel(
    const _Float16* __restrict__ Wh, int woff,
    const _Float16* __restrict__ Xn,
    _Float16* __restrict__ O0, _Float16* __restrict__ O1,
    _Float16* __restrict__ O2, float* __restrict__ Of, int nw) {
  const int zz = blockIdx.z;
  const int w = zz % nw;
  const int b = zz / nw;
  const _Float16* Wb = Wh + (size_t)(woff + w) * 65536;
  const _Float16* Bb = Xn + (size_t)b * BHN;
  const int o0 = blockIdx.y * 128;
  const int bn0 = blockIdx.x * 128;

  __shared__ __align__(16) _Float16 Ah[8192];  // [128][64], chunk-swizzled
  __shared__ __align__(16) _Float16 Bh[8192];

  const int tid = threadIdx.x;
  const int wave = tid >> 6;
  const int lane = tid & 63;
  const int lg = lane >> 4, ll = lane & 15;
  const int wm = wave >> 1, wn = wave & 1;

  f32x4 acc[4][4];
#pragma unroll
  for (int mi = 0; mi < 4; ++mi)
#pragma unroll
    for (int ni = 0; ni < 4; ++ni) acc[mi][ni] = (f32x4){0.f, 0.f, 0.f, 0.f};

  for (int k0 = 0; k0 < 256; k0 += 64) {
    // stage 128x64 per operand: 1024 16B-chunks, 4 per thread per operand.
    // LDS dest linear; source chunk pre-swizzled by ^(row&7).
#pragma unroll
    for (int i = 0; i < 4; ++i) {
      int e = tid + i * 256;          // chunk id 0..1023
      int r = e >> 3, cch = e & 7;
      int srcc = cch ^ (r & 7);
      _Float16* dst = &Ah[(size_t)(i * 256 + wave * 64) * 8];
      gl_lds16(Wb + (size_t)(o0 + r) * 256 + k0 + srcc * 8, dst);
      _Float16* dstb = &Bh[(size_t)(i * 256 + wave * 64) * 8];
      gl_lds16(Bb + (size_t)(bn0 + r) * 256 + k0 + srcc * 8, dstb);
    }
    __syncthreads();
#pragma unroll
    for (int kk = 0; kk < 2; ++kk) {
      half8 af[4], bf[4];
#pragma unroll
      for (int mi = 0; mi < 4; ++mi) {
        int row = wm * 64 + mi * 16 + ll;
        int ch = (kk * 4 + lg) ^ (row & 7);
        af[mi] = *(const half8*)&Ah[row * 64 + ch * 8];
      }
#pragma unroll
      for (int ni = 0; ni < 4; ++ni) {
        int row = wn * 64 + ni * 16 + ll;
        int ch = (kk * 4 + lg) ^ (row & 7);
        bf[ni] = *(const half8*)&Bh[row * 64 + ch * 8];
      }
#pragma unroll
      for (int mi = 0; mi < 4; ++mi)
#pragma unroll
        for (int ni = 0; ni < 4; ++ni)
          acc[mi][ni] = __builtin_amdgcn_mfma_f32_16x16x32_f16(
              af[mi], bf[ni], acc[mi][ni], 0, 0, 0);
    }
    __syncthreads();
  }

#pragma unroll
  for (int mi = 0; mi < 4; ++mi) {
#pragma unroll
    for (int ni = 0; ni < 4; ++ni) {
      int o = o0 + wm * 64 + mi * 16 + lg * 4;   // channel (4 consecutive via r)
      int mcol = bn0 + wn * 64 + ni * 16 + ll;   // dd*1024 + token
      if constexpr (MODE == 1) {
        float* Ofb = Of + (size_t)b * BHN;
#pragma unroll
        for (int r = 0; r < 4; ++r)
          Ofb[(size_t)(o + r) * 3072 + mcol] = acc[mi][ni][r];
      } else {
        const int h = o >> 5, i = o & 31;
        const int dd = mcol >> 10, tok = mcol & 1023;
        const size_t bh8 = (size_t)(b * 8 + h);
        if (w == 2) {
          // Vp[bh][t][kt][dt=dd][lq=i(+r)][hi2][e]
          int tt = tok >> 6, kk = tok & 63;
          int kt = kk >> 4, hi2 = (kk >> 3) & 1, e = kk & 7;
          size_t base = ((((bh8 * 16 + tt) * 4 + kt) * 3 + dd) * 512) +
                        (size_t)i * 16 + hi2 * 8 + e;
#pragma unroll
          for (int r = 0; r < 4; ++r)
            O2[base + r * 16] = (_Float16)acc[mi][ni][r];
        } else {
          int dperm = dd * 32 + i;
          int pp = dperm >> 3, j0 = i & 7;
          int ks = pp >> 1, hif = pp & 1;
          float qs = (w == 0) ? SCL2 : 1.0f;
          _Float16 t4[4];
#pragma unroll
          for (int r = 0; r < 4; ++r) t4[r] = (_Float16)(acc[mi][ni][r] * qs);
          size_t idx;
          if (w == 0) {
            // Qp[bh][qt32][ks][ql][hi][j]
            idx = ((bh8 * 32 + (tok >> 5)) * 6 + ks) * 512 +
                  (size_t)(tok & 31) * 16 + hif * 8 + j0;
            *(uint2*)&O0[idx] = *(uint2*)t4;
          } else {
            // Kp[bh][t][ks][kk][hi][j]
            idx = ((bh8 * 16 + (tok >> 6)) * 6 + ks) * 1024 +
                  (size_t)(tok & 63) * 16 + hif * 8 + j0;
            *(uint2*)&O1[idx] = *(uint2*)t4;
          }
        }
      }
    }
  }
}

// ---------------------------------------------------------------------------
// Flash attention — EXACT r9 structure (best measured: 46.9-47.3 us).
// 32x32 swapped-QK^T, LDS-free, barrier-free, packed fragment-major q/k/v
// (every fragment load = 64 lanes x 16B contiguous; K+V tile 12KB, L1-
// resident, shared by the block's 4 waves). V(t) issued early; K(t+1)
// reloads after QK^T(t). Softmax exp2 domain, defer-max THR=12, permlane
// P-repack. C/D map: col=lane&31, row=(r&3)+8*(r>>2)+4*(lane>>5).
// ---------------------------------------------------------------------------
__global__ __launch_bounds__(256, 2) void attn_kernel(
    const _Float16* __restrict__ Qp, const _Float16* __restrict__ Kp,
    const _Float16* __restrict__ Vp,
    const unsigned long long* __restrict__ mbits,
    _Float16* __restrict__ yT) {
  const int gid = blockIdx.x;
  const int bh = gid & 63;   // XCD = gid%8 = h: per-XCD K/V set L2-resident
  const int qt = gid >> 6;
  const int b = bh >> 3, h = bh & 7;
  const int n0 = qt * 128;

  const int tid = threadIdx.x;
  const int lane = tid & 63;
  const int wave = tid >> 6;
  const int hi = lane >> 5;
  const int lq = lane & 31;
  const int wq0 = wave * 32;

  const size_t bh8 = (size_t)(b * 8 + h);
  const int lo16 = lq * 16 + hi * 8;

  const _Float16* Qb = Qp + (bh8 * 32 + (qt * 4 + wave)) * 6 * 512 + lo16;
  half8 qf[6];
#pragma unroll
  for (int ks = 0; ks < 6; ++ks) qf[ks] = *(const half8*)(Qb + ks * 512);

  const _Float16* Kh = Kp + bh8 * 98304 + lo16;
  const _Float16* Vh = Vp + bh8 * 98304 + lo16;

  half8 kf[6][2];
  auto loadK = [&](int t) {
    const _Float16* Kt = Kh + t * 6144;
#pragma unroll
    for (int ks = 0; ks < 6; ++ks) {
      kf[ks][0] = *(const half8*)(Kt + ks * 1024);
      kf[ks][1] = *(const half8*)(Kt + ks * 1024 + 512);
    }
  };
  loadK(0);

  float M = 0.f, Lh = 0.f;
  f32x16 yacc[3];
#pragma unroll
  for (int dt = 0; dt < 3; ++dt)
#pragma unroll
    for (int r = 0; r < 16; ++r) yacc[dt][r] = 0.f;

  for (int t = 0; t < 16; ++t) {
    const _Float16* Vt = Vh + t * 6144;
    half8 vf[4][3];
#pragma unroll
    for (int kt = 0; kt < 4; ++kt)
#pragma unroll
      for (int dt = 0; dt < 3; ++dt)
        vf[kt][dt] = *(const half8*)(Vt + (kt * 3 + dt) * 512);

    const unsigned long long m64 = mbits[b * 16 + t];

    f32x16 s[2];
#pragma unroll
    for (int r = 0; r < 16; ++r) { s[0][r] = 0.f; s[1][r] = 0.f; }
    __builtin_amdgcn_s_setprio(1);
#pragma unroll
    for (int ks = 0; ks < 6; ++ks) {
      s[0] = __builtin_amdgcn_mfma_f32_32x32x16_f16(kf[ks][0], qf[ks], s[0],
                                                    0, 0, 0);
      s[1] = __builtin_amdgcn_mfma_f32_32x32x16_f16(kf[ks][1], qf[ks], s[1],
                                                    0, 0, 0);
    }
    __builtin_amdgcn_s_setprio(0);

    if (t + 1 < 16) loadK(t + 1);

    float mx = -1e30f;
#pragma unroll
    for (int nt = 0; nt < 2; ++nt) {
      unsigned wm = (unsigned)(m64 >> (nt * 32 + 4 * hi));
#pragma unroll
      for (int r = 0; r < 16; ++r) {
        float sv = s[nt][r];
        sv = ((wm >> ((r & 3) + 8 * (r >> 2))) & 1u) ? -1e30f : sv;
        s[nt][r] = sv;
        mx = fmaxf(mx, sv);
      }
    }
    if (__any(mx > M + 12.f)) {
      float mx2 = fmaxf(mx, __shfl_xor(mx, 32));
      float newM = fmaxf(M, mx2);
      float corr = ex2(M - newM);
      M = newM;
      Lh *= corr;
#pragma unroll
      for (int dt = 0; dt < 3; ++dt)
#pragma unroll
        for (int r = 0; r < 16; ++r) yacc[dt][r] *= corr;
    }
    float psum = 0.f;
#pragma unroll
    for (int nt = 0; nt < 2; ++nt)
#pragma unroll
      for (int r = 0; r < 16; ++r) {
        float p = ex2(s[nt][r] - M);
        s[nt][r] = p;
        psum += p;
      }
    Lh += psum;

#pragma unroll
    for (int nt = 0; nt < 2; ++nt) {
#pragma unroll
      for (int hf = 0; hf < 2; ++hf) {
        const int bs = hf * 8;
        unsigned A0 = pkh(s[nt][bs + 0], s[nt][bs + 1]);
        unsigned A1 = pkh(s[nt][bs + 2], s[nt][bs + 3]);
        unsigned B0 = pkh(s[nt][bs + 4], s[nt][bs + 5]);
        unsigned B1 = pkh(s[nt][bs + 6], s[nt][bs + 7]);
        plswap(A0, B0);
        plswap(A1, B1);
        PF pf;
        pf.u[0] = A0;
        pf.u[1] = A1;
        pf.u[2] = B0;
        pf.u[3] = B1;
        const int kt = nt * 2 + hf;
        __builtin_amdgcn_s_setprio(1);
#pragma unroll
        for (int dt = 0; dt < 3; ++dt)
          yacc[dt] = __builtin_amdgcn_mfma_f32_32x32x16_f16(
              vf[kt][dt], pf.v, yacc[dt], 0, 0, 0);
        __builtin_amdgcn_s_setprio(0);
      }
    }
  }

  float L = Lh + __shfl_xor(Lh, 32);
  float inv = (L > 0.f) ? 1.f / L : 0.f;
  _Float16* yb = yT + (size_t)b * BHN;
#pragma unroll
  for (int dt = 0; dt < 3; ++dt) {
    _Float16* rowp =
        yb + (size_t)(dt * 1024 + n0 + wq0 + lq) * 256 + h * 32 + hi * 4;
#pragma unroll
    for (int g = 0; g < 4; ++g) {
      _Float16 t4[4];
#pragma unroll
      for (int j = 0; j < 4; ++j)
        t4[j] = (_Float16)(yacc[dt][g * 4 + j] * inv);
      *(uint2*)(rowp + g * 8) = *(uint2*)t4;
    }
  }
}

// ---------------------------------------------------------------------------
extern "C" void kernel_launch(void* const* d_in, const int* in_sizes, int n_in,
                              void* d_out, int out_size, void* d_ws,
                              size_t ws_size, hipStream_t stream) {
  const float* x = (const float*)d_in[0];
  const float* Wq = (const float*)d_in[1];
  const float* Wk = (const float*)d_in[2];
  const float* Wv = (const float*)d_in[3];
  const float* Wp = (const float*)d_in[4];
  const unsigned* mask = (const unsigned*)d_in[5];
  float* out = (float*)d_out;

  _Float16* Wh = (_Float16*)d_ws;                   // 0.5 MB
  _Float16* XT = Wh + 4 * 65536;                    // 12.6 MB n-major
  _Float16* Qp = XT + (size_t)B_ * BHN;             // 12.6 MB packed frags
  _Float16* Kp = Qp + (size_t)B_ * BHN;             // 12.6 MB packed frags
  _Float16* Vp = Kp + (size_t)B_ * BHN;             // 12.6 MB packed frags
  _Float16* yT = Vp + (size_t)B_ * BHN;             // 12.6 MB n-major
  unsigned long long* mb = (unsigned long long*)(yT + (size_t)B_ * BHN);

  prep_kernel<<<dim3(48, 4, 9), 256, 0, stream>>>(x, XT, Wq, Wk, Wv, Wp, Wh,
                                                  mask, mb);

  dim3 g1(24, 2, B_ * 3);
  mgemm_kernel<0><<<g1, 256, 0, stream>>>(Wh, 0, XT, Qp, Kp, Vp, nullptr, 3);

  attn_kernel<<<dim3(512), 256, 0, stream>>>(Qp, Kp, Vp, mb, yT);

  dim3 g3(24, 2, B_);
  mgemm_kernel<1><<<g3, 256, 0, stream>>>(Wh, 3, yT, nullptr, nullptr, nullptr,
                                          out, 1);
}